// Round 14
// baseline (176.712 us; speedup 1.0000x reference)
//
#include <hip/hip_runtime.h>
#include <hip/hip_cooperative_groups.h>

namespace cg = cooperative_groups;

// Problem constants (B, N, K, P, D, F, H) = (8, 20, 2, 320, 3, 64, 64)
constexpr int B_ = 8, N_ = 20, K_ = 2, P_ = 320, D_ = 3, F_ = 64, H_ = 64;
constexpr int Q_ = K_ * P_;          // 640 rows = flattened (K,P)
constexpr float EPS_ = 1e-8f;
constexpr float LOG2E_ = 1.4426950408889634f;

// ---------------- Cooperative single-launch path ----------------
// 1280 blocks = 8 tiles x 80 rows per (b,n); __launch_bounds__(256,5) caps
// VGPR<=102 so 5 blocks/CU x 256 CU = 1280 co-resident (LDS 22.4KB -> 7/CU).
// wval stays in registers across grid.sync(); out written ONCE, normalized.
// Replay-safe: barrier state is runtime-managed; wsPart is write-then-read
// within the launch. NO inline asm (R3-R8 curse).
constexpr int CT_ = 8;               // tiles per bn
constexpr int CR_ = 80;              // rows per tile; tile>=4 -> k=1 (uniform)

__global__ __launch_bounds__(256, 5) void dnbp_coop(
    const float* __restrict__ X,      // (B,N,K,P,D)
    const float* __restrict__ W,      // (B,N,K,P)
    const float* __restrict__ feats,  // (B,N,F)
    const float* __restrict__ mu,     // (N,K,D)
    const float* __restrict__ W1,     // (N,F,H)
    const float* __restrict__ Wx,     // (N,D,H)
    const float* __restrict__ b1,     // (N,H)
    const float* __restrict__ W2,     // (N,H)
    const float* __restrict__ bias2,  // (N,)
    const int* __restrict__ nbr,      // (N,2)
    float* __restrict__ wsPart,       // (1280,) tile sums
    float* __restrict__ out)          // (B,N,K,P)
{
    __shared__ float4 sQ[Q_];            // neighbor point q: (x, y, z, c)
    __shared__ float4 aT[CR_];           // row: (4L*a0, 4L*a1, 4L*a2, -2L*|a|^2)
    __shared__ float4 xT[CR_];           // row: (x0, x1, x2, 0)
    __shared__ float4 gT[H_];            // h: (wx0, wx1, wx2, w2)
    __shared__ float  hbT[H_];           // h: hf + b1
    __shared__ float  gpart[H_][5];      // gemv f-segment partials (4 used)
    __shared__ float  tgate[CR_][5];     // gate h-segment partials (4 used)
    __shared__ float  part[CR_][17];     // row x slice partials (16 used)
    __shared__ float  red[4];
    __shared__ float  invW;              // 1/(sum W_neighbor + EPS)

    const int blk  = blockIdx.x;         // 0..1279
    const int bn   = blk >> 3;
    const int tile = blk & 7;
    const int b    = bn / N_;
    const int n    = bn - b * N_;
    const int tid  = threadIdx.x;        // 0..255
    const int wave = tid >> 6;
    const int lane = tid & 63;
    const int k    = (tile >= 4) ? 1 : 0;
    const int r0   = tile * CR_;         // row base in (k*320+p) flattening
    const int j    = nbr[n * 2 + k];     // component k pairs with neighbor k

    // ---- stage neighbor j's 640 points (vectorized: 4 points per thread) ----
    const size_t nbase = ((size_t)b * N_ + j) * Q_;
    float wsum = 0.f;
    if (tid < Q_ / 4) {                  // threads 0..159
        const int t = tid;
        const float4* xv = (const float4*)(X + nbase * D_);   // 16B-aligned
        const float4 f0 = xv[3 * t];
        const float4 f1 = xv[3 * t + 1];
        const float4 f2 = xv[3 * t + 2];
        const float4 w4 = ((const float4*)(W + nbase))[t];    // 16B-aligned
        const float c0 = w4.x * __builtin_amdgcn_exp2f(-2.f * LOG2E_ *
                         (f0.x * f0.x + f0.y * f0.y + f0.z * f0.z));
        const float c1 = w4.y * __builtin_amdgcn_exp2f(-2.f * LOG2E_ *
                         (f0.w * f0.w + f1.x * f1.x + f1.y * f1.y));
        const float c2 = w4.z * __builtin_amdgcn_exp2f(-2.f * LOG2E_ *
                         (f1.z * f1.z + f1.w * f1.w + f2.x * f2.x));
        const float c3 = w4.w * __builtin_amdgcn_exp2f(-2.f * LOG2E_ *
                         (f2.y * f2.y + f2.z * f2.z + f2.w * f2.w));
        sQ[4 * t]     = make_float4(f0.x, f0.y, f0.z, c0);
        sQ[4 * t + 1] = make_float4(f0.w, f1.x, f1.y, c1);
        sQ[4 * t + 2] = make_float4(f1.z, f1.w, f2.x, c2);
        sQ[4 * t + 3] = make_float4(f2.y, f2.z, f2.w, c3);
        wsum = (w4.x + w4.y) + (w4.z + w4.w);
    }
    {   // block-reduce neighbor weight sum (zeros from tid>=160)
        float v = wsum;
        #pragma unroll
        for (int off = 32; off > 0; off >>= 1) v += __shfl_down(v, off, 64);
        if (lane == 0) red[wave] = v;
    }

    // ---- hb gemv, parallel over 256 threads: h = tid&63, f-seg = tid>>6 ----
    {
        const int h = tid & 63, seg = tid >> 6;
        const float* fp  = feats + (size_t)bn * F_;
        const float* w1p = W1 + (size_t)n * F_ * H_ + h;
        float acc = 0.f;
        #pragma unroll
        for (int f = 0; f < 16; ++f) {
            const int ff = seg * 16 + f;
            acc = fmaf(fp[ff], w1p[(size_t)ff * H_], acc);
        }
        gpart[h][seg] = acc;
    }

    // ---- per-row params (threads 0..79) + gate tables (threads 0..63) ----
    if (tid < CR_) {
        const int gr = r0 + tid;         // flattened row of this (b,n)
        const float* xp = X + ((size_t)bn * Q_ + gr) * D_;
        const float x0 = xp[0], x1 = xp[1], x2 = xp[2];
        const float* mup = mu + (n * K_ + k) * D_;
        const float a0 = x0 - mup[0];
        const float a1 = x1 - mup[1];
        const float a2 = x2 - mup[2];
        const float ra2 = a0 * a0 + a1 * a1 + a2 * a2;
        aT[tid] = make_float4(a0 * (4.f * LOG2E_), a1 * (4.f * LOG2E_),
                              a2 * (4.f * LOG2E_), -2.f * LOG2E_ * ra2);
        xT[tid] = make_float4(x0, x1, x2, 0.f);
    }
    if (tid < H_) {
        const float* wxp = Wx + (size_t)n * D_ * H_ + tid;
        gT[tid] = make_float4(wxp[0], wxp[H_], wxp[2 * H_], W2[n * H_ + tid]);
    }
    __syncthreads();

    if (tid < H_)
        hbT[tid] = ((gpart[tid][0] + gpart[tid][1]) +
                    (gpart[tid][2] + gpart[tid][3])) + b1[n * H_ + tid];
    if (tid == 0)
        invW = 1.f / (((red[0] + red[1]) + (red[2] + red[3])) + EPS_);

    // ---- q-pass: thread = (row-group g: 5 rows, slice s: 40 strided q) ----
    const int g = tid >> 4;              // 0..15 (rows 5g..5g+4 of the tile)
    const int s = tid & 15;              // 0..15
    float S0[5], S1[5], S2[5], RA[5], acc[5];
    #pragma unroll
    for (int jj = 0; jj < 5; ++jj) {
        const float4 av = aT[g * 5 + jj];
        S0[jj] = av.x; S1[jj] = av.y; S2[jj] = av.z; RA[jj] = av.w;
        acc[jj] = 0.f;
    }
    #pragma unroll 4
    for (int i = 0; i < Q_ / 16; ++i) {  // 40 q per thread
        const float4 Pq = sQ[i * 16 + s];
        #pragma unroll
        for (int jj = 0; jj < 5; ++jj) {
            const float d = fmaf(Pq.x, S0[jj],
                            fmaf(Pq.y, S1[jj],
                            fmaf(Pq.z, S2[jj], RA[jj])));
            acc[jj] = fmaf(Pq.w, __builtin_amdgcn_exp2f(d), acc[jj]);
        }
    }
    #pragma unroll
    for (int jj = 0; jj < 5; ++jj)
        part[g * 5 + jj][s] = acc[jj];

    __syncthreads();

    // ---- gate phase A, parallel: rows 0..63 by all threads, 64..79 by wave 0 ----
    {
        const int row = tid & 63, seg = tid >> 6;
        const float4 xr = xT[row];
        float accg = 0.f;
        #pragma unroll
        for (int hh = 0; hh < 16; ++hh) {
            const int h = seg * 16 + hh;
            const float4 gv = gT[h];
            float t = fmaf(xr.x, gv.x, fmaf(xr.y, gv.y, fmaf(xr.z, gv.z, hbT[h])));
            t = fmaxf(t, 0.f);
            accg = fmaf(t, gv.w, accg);
        }
        tgate[row][seg] = accg;
    }
    if (tid < 64) {
        const int row = 64 + (tid & 15), seg = tid >> 4;
        const float4 xr = xT[row];
        float accg = 0.f;
        #pragma unroll
        for (int hh = 0; hh < 16; ++hh) {
            const int h = seg * 16 + hh;
            const float4 gv = gT[h];
            float t = fmaf(xr.x, gv.x, fmaf(xr.y, gv.y, fmaf(xr.z, gv.z, hbT[h])));
            t = fmaxf(t, 0.f);
            accg = fmaf(t, gv.w, accg);
        }
        tgate[row][seg] = accg;
    }
    __syncthreads();

    // ---- phase B: threads 0..79 compute wval (kept in registers) ----
    float wval = 0.f;
    if (tid < CR_) {
        const int row = tid;
        const float* pr = part[row];
        const float msg =
            (((pr[0] + pr[1]) + (pr[2] + pr[3])) + ((pr[4] + pr[5]) + (pr[6] + pr[7]))) +
            (((pr[8] + pr[9]) + (pr[10] + pr[11])) + ((pr[12] + pr[13]) + (pr[14] + pr[15])));
        const float accg = bias2[n] + ((tgate[row][0] + tgate[row][1]) +
                                       (tgate[row][2] + tgate[row][3]));
        const float u = 1.f / (1.f + __expf(-accg));
        wval = u * msg * invW;           // invW: exact linear factor
    }
    // block-reduce wval over threads 0..79 (others contribute 0)
    {
        float v = wval;
        #pragma unroll
        for (int off = 32; off > 0; off >>= 1) v += __shfl_down(v, off, 64);
        if (lane == 0) red[wave] = v;
        __syncthreads();
        if (tid == 0)
            wsPart[blk] = (red[0] + red[1]) + (red[2] + red[3]);
    }

    cg::this_grid().sync();

    // ---- read bn's 8 tile partials, write normalized output once ----
    if (tid < CR_) {
        const float* p = wsPart + bn * CT_;
        const float ssum = ((p[0] + p[1]) + (p[2] + p[3])) +
                           ((p[4] + p[5]) + (p[6] + p[7]));
        const float inv = 1.f / (ssum + EPS_);
        out[(size_t)bn * Q_ + r0 + tid] = wval * inv;
    }
}

// ---------------- Fallback: proven R13 two-kernel path (88.71us) ----------------
constexpr int TILES_ = 10;
constexpr int ROWS_  = 64;

__global__ __launch_bounds__(256) void main_kernel(
    const float* __restrict__ X, const float* __restrict__ W,
    const float* __restrict__ feats, const float* __restrict__ mu,
    const float* __restrict__ W1, const float* __restrict__ Wx,
    const float* __restrict__ b1, const float* __restrict__ W2,
    const float* __restrict__ bias2, const int* __restrict__ nbr,
    float* __restrict__ wsPart, float* __restrict__ out)
{
    __shared__ float4 sQ[Q_];
    __shared__ float4 aT[ROWS_];
    __shared__ float4 xT[ROWS_];
    __shared__ float4 gT[H_];
    __shared__ float  hbT[H_];
    __shared__ float  gpart[H_][5];
    __shared__ float  tgate[ROWS_][5];
    __shared__ float  part[ROWS_][17];
    __shared__ float  red[4];
    __shared__ float  invW;

    const int blk  = blockIdx.x;
    const int bn   = blk / TILES_;
    const int tile = blk - bn * TILES_;
    const int b    = bn / N_;
    const int n    = bn - b * N_;
    const int tid  = threadIdx.x;
    const int wave = tid >> 6;
    const int lane = tid & 63;
    const int k    = (tile >= 5) ? 1 : 0;
    const int r0   = tile * ROWS_;
    const int j    = nbr[n * 2 + k];

    const size_t nbase = ((size_t)b * N_ + j) * Q_;
    float wsum = 0.f;
    if (tid < Q_ / 4) {
        const int t = tid;
        const float4* xv = (const float4*)(X + nbase * D_);
        const float4 f0 = xv[3 * t];
        const float4 f1 = xv[3 * t + 1];
        const float4 f2 = xv[3 * t + 2];
        const float4 w4 = ((const float4*)(W + nbase))[t];
        const float c0 = w4.x * __builtin_amdgcn_exp2f(-2.f * LOG2E_ *
                         (f0.x * f0.x + f0.y * f0.y + f0.z * f0.z));
        const float c1 = w4.y * __builtin_amdgcn_exp2f(-2.f * LOG2E_ *
                         (f0.w * f0.w + f1.x * f1.x + f1.y * f1.y));
        const float c2 = w4.z * __builtin_amdgcn_exp2f(-2.f * LOG2E_ *
                         (f1.z * f1.z + f1.w * f1.w + f2.x * f2.x));
        const float c3 = w4.w * __builtin_amdgcn_exp2f(-2.f * LOG2E_ *
                         (f2.y * f2.y + f2.z * f2.z + f2.w * f2.w));
        sQ[4 * t]     = make_float4(f0.x, f0.y, f0.z, c0);
        sQ[4 * t + 1] = make_float4(f0.w, f1.x, f1.y, c1);
        sQ[4 * t + 2] = make_float4(f1.z, f1.w, f2.x, c2);
        sQ[4 * t + 3] = make_float4(f2.y, f2.z, f2.w, c3);
        wsum = (w4.x + w4.y) + (w4.z + w4.w);
    }
    {
        float v = wsum;
        #pragma unroll
        for (int off = 32; off > 0; off >>= 1) v += __shfl_down(v, off, 64);
        if (lane == 0) red[wave] = v;
    }
    {
        const int h = tid & 63, seg = tid >> 6;
        const float* fp  = feats + (size_t)bn * F_;
        const float* w1p = W1 + (size_t)n * F_ * H_ + h;
        float acc = 0.f;
        #pragma unroll
        for (int f = 0; f < 16; ++f) {
            const int ff = seg * 16 + f;
            acc = fmaf(fp[ff], w1p[(size_t)ff * H_], acc);
        }
        gpart[h][seg] = acc;
    }
    if (tid < ROWS_) {
        const int gr = r0 + tid;
        const float* xp = X + ((size_t)bn * Q_ + gr) * D_;
        const float x0 = xp[0], x1 = xp[1], x2 = xp[2];
        const float* mup = mu + (n * K_ + k) * D_;
        const float a0 = x0 - mup[0];
        const float a1 = x1 - mup[1];
        const float a2 = x2 - mup[2];
        const float ra2 = a0 * a0 + a1 * a1 + a2 * a2;
        aT[tid] = make_float4(a0 * (4.f * LOG2E_), a1 * (4.f * LOG2E_),
                              a2 * (4.f * LOG2E_), -2.f * LOG2E_ * ra2);
        xT[tid] = make_float4(x0, x1, x2, 0.f);
        const float* wxp = Wx + (size_t)n * D_ * H_ + tid;
        gT[tid] = make_float4(wxp[0], wxp[H_], wxp[2 * H_], W2[n * H_ + tid]);
    }
    __syncthreads();

    if (tid < H_)
        hbT[tid] = ((gpart[tid][0] + gpart[tid][1]) +
                    (gpart[tid][2] + gpart[tid][3])) + b1[n * H_ + tid];
    if (tid == 0)
        invW = 1.f / (((red[0] + red[1]) + (red[2] + red[3])) + EPS_);

    const int g = tid >> 4;
    const int s = tid & 15;
    float S0[4], S1[4], S2[4], RA[4], acc[4];
    #pragma unroll
    for (int jj = 0; jj < 4; ++jj) {
        const float4 av = aT[g * 4 + jj];
        S0[jj] = av.x; S1[jj] = av.y; S2[jj] = av.z; RA[jj] = av.w;
        acc[jj] = 0.f;
    }
    #pragma unroll 4
    for (int i = 0; i < Q_ / 16; ++i) {
        const float4 Pq = sQ[i * 16 + s];
        #pragma unroll
        for (int jj = 0; jj < 4; ++jj) {
            const float d = fmaf(Pq.x, S0[jj],
                            fmaf(Pq.y, S1[jj],
                            fmaf(Pq.z, S2[jj], RA[jj])));
            acc[jj] = fmaf(Pq.w, __builtin_amdgcn_exp2f(d), acc[jj]);
        }
    }
    #pragma unroll
    for (int jj = 0; jj < 4; ++jj)
        part[g * 4 + jj][s] = acc[jj];

    __syncthreads();

    {
        const int row = tid & 63, seg = tid >> 6;
        const float4 xr = xT[row];
        float accg = 0.f;
        #pragma unroll
        for (int hh = 0; hh < 16; ++hh) {
            const int h = seg * 16 + hh;
            const float4 gv = gT[h];
            float t = fmaf(xr.x, gv.x, fmaf(xr.y, gv.y, fmaf(xr.z, gv.z, hbT[h])));
            t = fmaxf(t, 0.f);
            accg = fmaf(t, gv.w, accg);
        }
        tgate[row][seg] = accg;
    }
    __syncthreads();

    if (tid < ROWS_) {
        const int row = tid;
        const float* pr = part[row];
        const float msg =
            (((pr[0] + pr[1]) + (pr[2] + pr[3])) + ((pr[4] + pr[5]) + (pr[6] + pr[7]))) +
            (((pr[8] + pr[9]) + (pr[10] + pr[11])) + ((pr[12] + pr[13]) + (pr[14] + pr[15])));
        const float accg = bias2[n] + ((tgate[row][0] + tgate[row][1]) +
                                       (tgate[row][2] + tgate[row][3]));
        const float u = 1.f / (1.f + __expf(-accg));
        const float wval = u * msg * invW;
        out[(size_t)bn * Q_ + r0 + row] = wval;
        float v = wval;
        #pragma unroll
        for (int off = 32; off > 0; off >>= 1) v += __shfl_down(v, off, 64);
        if (tid == 0) wsPart[blk] = v;
    }
}

__global__ __launch_bounds__(Q_) void norm_kernel(
    const float* __restrict__ wsPart, float* __restrict__ out)
{
    const int bn = blockIdx.x;
    const float* p = wsPart + bn * TILES_;
    float s0 = 0.f, s1 = 0.f;
    #pragma unroll
    for (int t = 0; t < TILES_ / 2; ++t) { s0 += p[2 * t]; s1 += p[2 * t + 1]; }
    const float inv = 1.f / ((s0 + s1) + EPS_);
    out[(size_t)bn * Q_ + threadIdx.x] *= inv;
}

extern "C" void kernel_launch(void* const* d_in, const int* in_sizes, int n_in,
                              void* d_out, int out_size, void* d_ws, size_t ws_size,
                              hipStream_t stream) {
    const float* X     = (const float*)d_in[0];
    const float* W     = (const float*)d_in[1];
    const float* feats = (const float*)d_in[2];
    const float* mu    = (const float*)d_in[3];
    const float* W1    = (const float*)d_in[4];
    const float* Wx    = (const float*)d_in[5];
    const float* b1    = (const float*)d_in[6];
    const float* W2    = (const float*)d_in[7];
    const float* bias2 = (const float*)d_in[8];
    const int*   nbr   = (const int*)d_in[9];
    float*       out   = (float*)d_out;
    float*       wsPart = (float*)d_ws;

    void* args[] = {(void*)&X, (void*)&W, (void*)&feats, (void*)&mu,
                    (void*)&W1, (void*)&Wx, (void*)&b1, (void*)&W2,
                    (void*)&bias2, (void*)&nbr, (void*)&wsPart, (void*)&out};
    const hipError_t err = hipLaunchCooperativeKernel(
        (const void*)dnbp_coop, dim3(B_ * N_ * CT_), dim3(256), args, 0, stream);

    if (err != hipSuccess) {
        // fallback: proven R13 two-kernel path
        main_kernel<<<B_ * N_ * TILES_, 256, 0, stream>>>(
            X, W, feats, mu, W1, Wx, b1, W2, bias2, nbr, wsPart, out);
        norm_kernel<<<B_ * N_, Q_, 0, stream>>>(wsPart, out);
    }
}